// Round 1
// baseline (187.111 us; speedup 1.0000x reference)
//
#include <hip/hip_runtime.h>
#include <math.h>

namespace {
constexpr int   NB   = 25;     // basis functions
constexpr int   TS   = 301;    // time steps
constexpr int   TPAD = 304;    // padded table stride
constexpr float DT   = 0.01f;
constexpr float TAU  = 3.0f;
constexpr float AX   = 2.0f;
constexpr float AZ   = 48.0f;
constexpr float BZ   = 12.0f;  // AZ/4
constexpr int   ROWS = 131072; // BATCH * DOF
}

// ws layout (floats): [0..TPAD) = A_t, [TPAD..2*TPAD) = B_t,
//                     [(2+n)*TPAD + t] = H_t[n]
__global__ __launch_bounds__(512)
void dmp_precompute(const float* __restrict__ c, const float* __restrict__ s2,
                    float* __restrict__ ws) {
  __shared__ float g[TS][NB];
  __shared__ float cS[NB], vS[NB];
  const int tid = threadIdx.x;
  if (tid < NB) { cS[tid] = c[tid]; vS[tid] = s2[tid]; }
  __syncthreads();
  const float q = 1.0f - AX / TAU * DT;   // cx multiplier per step
  for (int i = tid; i < TS; i += 512) {
    // cx after (i+1) updates (reference updates cx BEFORE using it)
    float cx = powf(q, (float)(i + 1));
    float p[NB]; float sum = 0.f;
    #pragma unroll
    for (int n = 0; n < NB; ++n) {
      float d = cx - cS[n];
      p[n] = expf(-0.5f * d * d / vS[n]);
      sum += p[n];
    }
    float m = cx / sum;
    #pragma unroll
    for (int n = 0; n < NB; ++n) g[i][n] = p[n] * m;
  }
  __syncthreads();
  // 27 independent linear-response recurrences (lanes 0..26 of wave 0)
  if (tid < NB + 2) {
    float y, gl;
    if (tid == 0)      { y = 1.f; gl = 0.f; }   // response to y0
    else if (tid == 1) { y = 0.f; gl = 1.f; }   // response to goal
    else               { y = 0.f; gl = 0.f; }   // response to unit w_n
    float z = 0.f;
    const int nn = (tid >= 2) ? (tid - 2) : 0;
    float* dst = ws + tid * TPAD;
    for (int t = 0; t < TS; ++t) {
      float fx = (tid >= 2) ? g[t][nn] : 0.f;
      float dy = z / TAU;
      float dz = (AZ * (BZ * (gl - y) - z) + fx) / TAU;
      y += dy * DT;
      z += dz * DT;
      dst[t] = y;
    }
  }
}

// Each wave: one 64-wide t-chunk (lane = t), loops over 64 rows.
// h (25 floats, per-lane) held in VGPRs, scale pre-folded per-dof;
// row data (w, y0, goal) is wave-uniform -> scalar loads.
// Stores are fully coalesced: 64 consecutive t per instruction.
__global__ __launch_bounds__(256)
void dmp_main(const float* __restrict__ x, const float* __restrict__ scale,
              const float* __restrict__ ws, float* __restrict__ out) {
  const int lane = threadIdx.x & 63;
  const int wv   = (blockIdx.x << 2) + (threadIdx.x >> 6);
  const int tc   = wv % 5;          // t-chunk 0..4
  const int rg   = wv / 5;          // row group 0..2047 (64 rows each)
  const int t    = tc * 64 + lane;
  const int tl   = (t < TS) ? t : (TS - 1);
  const bool tv  = (t < TS);

  const float a = ws[tl];
  const float b = ws[TPAD + tl];
  float h0[NB], h1[NB];
  #pragma unroll
  for (int k = 0; k < NB; ++k) {
    float h = ws[(2 + k) * TPAD + tl];
    h0[k] = h * scale[2 + k];        // dof 0
    h1[k] = h * scale[27 + 2 + k];   // dof 1
  }
  const float s00 = scale[0],  s01 = scale[1];
  const float s10 = scale[27], s11 = scale[28];

  const int row0 = rg << 6;
  for (int rr = 0; rr < 64; rr += 2) {
    const int r0 = row0 + rr;                 // even row (dof 0)
    const float* xe = x + (size_t)r0 * 27;
    const float* xo = xe + 27;                // odd row (dof 1)
    float acc0 = 0.f, acc1 = 0.f;
    #pragma unroll
    for (int k = 0; k < NB; ++k) {
      acc0 = fmaf(xe[2 + k], h0[k], acc0);
      acc1 = fmaf(xo[2 + k], h1[k], acc1);
    }
    float y00 = xe[0] * s00, g0 = xe[1] * s01;
    float y01 = xo[0] * s10, g1 = xo[1] * s11;
    float yA = fmaf(a, y00, b * g0) + (g0 - y00) * acc0;
    float yB = fmaf(a, y01, b * g1) + (g1 - y01) * acc1;
    if (tv) {
      out[(size_t)r0 * TS + t]       = yA;
      out[(size_t)(r0 + 1) * TS + t] = yB;
    }
  }
}

extern "C" void kernel_launch(void* const* d_in, const int* in_sizes, int n_in,
                              void* d_out, int out_size, void* d_ws, size_t ws_size,
                              hipStream_t stream) {
  const float* x  = (const float*)d_in[0];
  const float* c  = (const float*)d_in[1];
  const float* s2 = (const float*)d_in[2];
  const float* sc = (const float*)d_in[3];
  float* ws  = (float*)d_ws;   // needs 27*304*4 = 32,832 bytes
  float* out = (float*)d_out;

  hipLaunchKernelGGL(dmp_precompute, dim3(1), dim3(512), 0, stream, c, s2, ws);

  const int nwaves = 5 * (ROWS / 64);              // 10240 waves
  hipLaunchKernelGGL(dmp_main, dim3(nwaves / 4), dim3(256), 0, stream,
                     x, sc, ws, out);
}

// Round 2
// 81.084 us; speedup vs baseline: 2.3076x; 2.3076x over previous
//
#include <hip/hip_runtime.h>
#include <math.h>

namespace {
constexpr int   NB   = 25;     // basis functions
constexpr int   TS   = 301;    // time steps
constexpr int   TPAD = 304;    // padded table stride
constexpr float DT   = 0.01f;
constexpr float TAU  = 3.0f;
constexpr float AX   = 2.0f;
constexpr float AZ   = 48.0f;
constexpr float BZ   = 12.0f;  // AZ/4
constexpr int   ROWS = 131072; // BATCH * DOF
}

// ws layout (floats): [0..TPAD) = A_t, [TPAD..2*TPAD) = B_t,
//                     [(2+n)*TPAD + t] = H_t[n]
__global__ __launch_bounds__(512)
void dmp_precompute(const float* __restrict__ c, const float* __restrict__ s2,
                    float* __restrict__ ws) {
  __shared__ float g[TS][NB];
  __shared__ float cS[NB], vS[NB];
  const int tid = threadIdx.x;
  if (tid < NB) { cS[tid] = c[tid]; vS[tid] = s2[tid]; }
  __syncthreads();
  const float q = 1.0f - AX / TAU * DT;   // cx multiplier per step
  for (int i = tid; i < TS; i += 512) {
    float cx = powf(q, (float)(i + 1));   // cx updated BEFORE use in ref
    float p[NB]; float sum = 0.f;
    #pragma unroll
    for (int n = 0; n < NB; ++n) {
      float d = cx - cS[n];
      p[n] = expf(-0.5f * d * d / vS[n]);
      sum += p[n];
    }
    float m = cx / sum;
    #pragma unroll
    for (int n = 0; n < NB; ++n) g[i][n] = p[n] * m;
  }
  __syncthreads();
  // 27 independent linear-response recurrences (lanes 0..26)
  if (tid < NB + 2) {
    float y, gl;
    if (tid == 0)      { y = 1.f; gl = 0.f; }   // response to y0
    else if (tid == 1) { y = 0.f; gl = 1.f; }   // response to goal
    else               { y = 0.f; gl = 0.f; }   // response to unit w_n
    float z = 0.f;
    const int nn = (tid >= 2) ? (tid - 2) : 0;
    float* dst = ws + tid * TPAD;
    for (int t = 0; t < TS; ++t) {
      float fx = (tid >= 2) ? g[t][nn] : 0.f;
      float dy = z / TAU;
      float dz = (AZ * (BZ * (gl - y) - z) + fx) / TAU;
      y += dy * DT;
      z += dz * DT;
      dst[t] = y;
    }
  }
}

// Block = 320 threads = 5 waves (one per 64-t chunk), 64 rows per block.
// Stage: coalesced global->LDS of the 64x27 x-slice, scale folded in,
// padded to 32 floats/row so w-coeffs are 16B-aligned -> ds_read_b128
// uniform broadcasts in the row loop (8 LDS instrs/row vs 54 VMEM before).
__global__ __launch_bounds__(320)
void dmp_main(const float* __restrict__ x, const float* __restrict__ scale,
              const float* __restrict__ ws, float* __restrict__ out) {
  __shared__ float4 xs[64][8];   // per row: [0]={y0s,gs,-,-}, [1..6]=w0..w23, [7].x=w24
  const int tid = threadIdx.x;
  const int rg  = blockIdx.x;                       // row group (64 rows)
  const float* __restrict__ xsrc = x + (size_t)rg * 64 * 27;
  float* xl = (float*)xs;
  for (int e = tid; e < 64 * 27; e += 320) {
    int r = e / 27;
    int k = e - r * 27;
    float v = xsrc[e] * scale[(r & 1) * 27 + k];
    xl[r * 32 + (k < 2 ? k : k + 2)] = v;
  }
  __syncthreads();

  const int lane = tid & 63;
  const int tc   = tid >> 6;          // 0..4
  const int t    = tc * 64 + lane;
  const int tl   = (t < TS) ? t : (TS - 1);
  const bool tv  = (t < TS);

  const float a = ws[tl];
  const float b = ws[TPAD + tl];
  float h[NB];
  #pragma unroll
  for (int k = 0; k < NB; ++k) h[k] = ws[(2 + k) * TPAD + tl];

  const int row0 = rg << 6;
  for (int rr = 0; rr < 64; rr += 2) {
    const float4 hd0 = xs[rr][0];
    const float4 hd1 = xs[rr + 1][0];
    float accA0 = 0.f, accA1 = 0.f;   // two accumulators per row (ILP)
    float accB0 = 0.f, accB1 = 0.f;
    #pragma unroll
    for (int q4 = 0; q4 < 6; ++q4) {
      const float4 w0 = xs[rr][1 + q4];
      const float4 w1 = xs[rr + 1][1 + q4];
      const int k0 = q4 * 4;
      accA0 = fmaf(w0.x, h[k0 + 0], accA0);
      accA1 = fmaf(w0.y, h[k0 + 1], accA1);
      accA0 = fmaf(w0.z, h[k0 + 2], accA0);
      accA1 = fmaf(w0.w, h[k0 + 3], accA1);
      accB0 = fmaf(w1.x, h[k0 + 0], accB0);
      accB1 = fmaf(w1.y, h[k0 + 1], accB1);
      accB0 = fmaf(w1.z, h[k0 + 2], accB0);
      accB1 = fmaf(w1.w, h[k0 + 3], accB1);
    }
    accA0 = fmaf(xs[rr][7].x,     h[24], accA0);
    accB0 = fmaf(xs[rr + 1][7].x, h[24], accB0);
    const float accA = accA0 + accA1;
    const float accB = accB0 + accB1;

    const float y0A = hd0.x, gA = hd0.y;
    const float y0B = hd1.x, gB = hd1.y;
    const float yA = fmaf(a, y0A, b * gA) + (gA - y0A) * accA;
    const float yB = fmaf(a, y0B, b * gB) + (gB - y0B) * accB;
    if (tv) {
      out[(size_t)(row0 + rr) * TS + t]     = yA;
      out[(size_t)(row0 + rr + 1) * TS + t] = yB;
    }
  }
}

extern "C" void kernel_launch(void* const* d_in, const int* in_sizes, int n_in,
                              void* d_out, int out_size, void* d_ws, size_t ws_size,
                              hipStream_t stream) {
  const float* x  = (const float*)d_in[0];
  const float* c  = (const float*)d_in[1];
  const float* s2 = (const float*)d_in[2];
  const float* sc = (const float*)d_in[3];
  float* ws  = (float*)d_ws;   // needs 27*304*4 = 32,832 bytes
  float* out = (float*)d_out;

  hipLaunchKernelGGL(dmp_precompute, dim3(1), dim3(512), 0, stream, c, s2, ws);
  hipLaunchKernelGGL(dmp_main, dim3(ROWS / 64), dim3(320), 0, stream,
                     x, sc, ws, out);
}